// Round 9
// baseline (2485.748 us; speedup 1.0000x reference)
//
#include <hip/hip_runtime.h>

typedef __attribute__((ext_vector_type(8))) short short8;
typedef __attribute__((ext_vector_type(4))) float floatx4;
typedef __attribute__((ext_vector_type(4))) unsigned int uint32x4;

#define NROWS 32768L          // padded row count (real pair rows = 32767)
#define NVALID 32767L
#define HGDIM 1024

__device__ __forceinline__ unsigned short f2bf_rne(float f) {
    union { float f; unsigned u; } v; v.f = f;
    unsigned r = v.u + 0x7fffu + ((v.u >> 16) & 1u);
    return (unsigned short)(r >> 16);
}

__device__ __forceinline__ void gload_lds16(const void* g, void* l) {
    __builtin_amdgcn_global_load_lds(
        (const __attribute__((address_space(1))) void*)g,
        (__attribute__((address_space(3))) void*)l,
        16, 0, 0);
}

// ---- convert x (fp32) -> bf16, zero-padding one extra row ----
__global__ void cvt_x(const float* __restrict__ x, unsigned short* __restrict__ xb,
                      long nx, long ntot4) {
    long i = (long)blockIdx.x * 256 + threadIdx.x;
    if (i >= ntot4) return;
    long i4 = i * 4;
    float4 v = make_float4(0.f, 0.f, 0.f, 0.f);
    if (i4 < nx) v = *(const float4*)(x + i4);
    ushort4 o;
    o.x = f2bf_rne(v.x); o.y = f2bf_rne(v.y); o.z = f2bf_rne(v.z); o.w = f2bf_rne(v.w);
    *(ushort4*)(xb + i4) = o;
}

// ---- W (K x N, fp32, row-major) -> Wt (N x K, bf16, row-major) ----
__global__ void transpose_cvt(const float* __restrict__ W, unsigned short* __restrict__ Wt,
                              int K, int N) {
    __shared__ float tile[32][33];
    int tx = threadIdx.x & 31, ty = threadIdx.x >> 5;   // 32 x 8
    int nb = blockIdx.x * 32, kb = blockIdx.y * 32;
    #pragma unroll
    for (int i = 0; i < 32; i += 8)
        tile[ty + i][tx] = W[(size_t)(kb + ty + i) * N + (nb + tx)];
    __syncthreads();
    #pragma unroll
    for (int i = 0; i < 32; i += 8)
        Wt[(size_t)(nb + ty + i) * K + (kb + tx)] = f2bf_rne(tile[tx][ty + i]);
}

// ---- small fp32 FC partial ----
template<bool RELU_IN>
__global__ void fc_partial(const float* __restrict__ in, const float* __restrict__ W,
                           const float* __restrict__ bias, float* __restrict__ out,
                           int N) {
    __shared__ float s_in[128];
    int j = blockIdx.x * 256 + threadIdx.x;
    int k0 = blockIdx.y * 128;
    if (threadIdx.x < 128) {
        float v = in[k0 + threadIdx.x];
        if (RELU_IN) v = fmaxf(v, 0.f);
        s_in[threadIdx.x] = v;
    }
    __syncthreads();
    float acc = (blockIdx.y == 0) ? bias[j] : 0.f;
    #pragma unroll 4
    for (int k = 0; k < 128; ++k)
        acc += s_in[k] * W[(size_t)(k0 + k) * N + j];
    atomicAdd(&out[j], acc);
}

// ================== 256x256 4-phase/K-tile bf16 MFMA GEMM, 64KB LDS ==============
// A in LDS (dbuf, per-K-half panels); B direct global->VGPR (L2-resident).
// 2 blocks/CU co-resident. Counted vmcnt per phase end (4/2/6/2), lgkmcnt(4).
// C(m,n) = A(m x K) * Bt(n x K)^T.  COLSUM=0: Hout=relu(C+bias) bf16 ld=1024.
// COLSUM=1: masked column-sum of relu(C+bias) atomicAdd into emb.

#define SBAR() __builtin_amdgcn_sched_barrier(0)

#define P_PRE() do { SBAR(); __builtin_amdgcn_s_barrier(); \
    asm volatile("s_waitcnt lgkmcnt(4)" ::: "memory"); SBAR(); \
    __builtin_amdgcn_s_setprio(1); } while (0)

#define P_POSTC(N) do { __builtin_amdgcn_s_setprio(0); SBAR(); \
    asm volatile("s_waitcnt vmcnt(" #N ")" ::: "memory"); SBAR(); \
    __builtin_amdgcn_s_barrier(); SBAR(); } while (0)

// stage one K-half panel (256 rows x 32 cols = 16KB) of tile T into buf.
#define STAGE_K(buf, kk, T) do { \
    const unsigned short* _g = gAs + (size_t)(T) * 64 + (kk) * 32; \
    char* _d = (char*)lds + ((((buf) * 2 + (kk))) << 14) + t * 16; \
    gload_lds16(_g, _d); \
    gload_lds16(_g + (size_t)128 * lda, _d + 8192); } while (0)

// read one A fragment group (4 m-subtiles) from panel (buf,kk), m-group g (0 or 1)
#define LDA4N(dst, buf, kk, g) do { _Pragma("unroll") for (int _q = 0; _q < 4; ++_q) \
    dst[_q] = *(const short8*)((const char*)lds + ((((buf) * 2 + (kk))) << 14) + abase + (((g) * 4 + _q) << 10)); } while (0)

// load one B fragment group (4 n-subtiles) direct from global (L2-hot)
#define BGLD(dst, T, kk) do { _Pragma("unroll") for (int _nf = 0; _nf < 4; ++_nf) \
    dst[_nf] = *(const short8*)(bBase + (size_t)_nf * 16 * ldb + (T) * 64 + (kk) * 32); } while (0)

#define MFMA16(AF, BF, MO) do { _Pragma("unroll") for (int _mf = 0; _mf < 4; ++_mf) { \
    _Pragma("unroll") for (int _nf = 0; _nf < 4; ++_nf) \
        acc[(MO) + _mf][_nf] = __builtin_amdgcn_mfma_f32_16x16x32_bf16(AF[_mf], BF[_nf], acc[(MO) + _mf][_nf], 0, 0, 0); } } while (0)

template<int COLSUM>
__global__ __launch_bounds__(512, 4)
void gemmQ(const unsigned short* __restrict__ A, int lda,
           const unsigned short* __restrict__ Bt, int ldb,
           const float* __restrict__ bias, int K,
           unsigned short* __restrict__ Hout,
           float* __restrict__ emb, long row0g, long nvalid,
           int mblocks) {
    __shared__ alignas(16) unsigned short lds[2][2][256][32];  // 64 KiB: [buf][khalf][row][col]

    const int t = threadIdx.x;        // 0..511
    // XCD-aware swizzle (bijective since nwg % 8 == 0); n-fastest within chunk
    int nwg = gridDim.x, bid = blockIdx.x, swz;
    if ((nwg & 7) == 0) { int cpx = nwg >> 3; swz = (bid & 7) * cpx + (bid >> 3); }
    else swz = bid;
    const int mb = swz >> 2, nb = swz & 3;
    const long m0 = (long)mb * 256;
    const int n0 = nb * 256;

    const int lane = t & 63;
    const int wv = t >> 6;
    const int wm = wv >> 2, wn = wv & 3;              // 2 M-waves x 4 N-waves
    // A fragment byte offset within a panel: row = wm*128 + (lane&15) (+m*16),
    // chunk = (lane>>4) ^ (row&3) = (lane>>4) ^ (lane&3)
    const int abase = (wm * 128 + (lane & 15)) * 64 + ((((lane >> 4) ^ (lane & 3))) << 4);
    // B direct-load base: row n, k-chunk (lane>>4)*8
    const unsigned short* bBase = Bt + (size_t)(n0 + wn * 64 + (lane & 15)) * ldb + ((lane >> 4) << 3);

    // A staging: thread t covers panel row t>>2, chunk t&3; source chunk pre-swizzled
    const int srA = t >> 2;
    const unsigned short* gAs = A + (size_t)(m0 + srA) * lda + (((t & 3) ^ (srA & 3)) << 3);

    floatx4 acc[8][4] = {};
    short8 aP[4], aQ[4], bK0[4], bK1[4];

    const int NT = K >> 6;            // 64-wide K tiles (8 or 16)

    // prologue: S0(0), bK0(0), S1(0); prove S0+bK0 (leave S1 in flight); read A03k0(0)
    STAGE_K(0, 0, 0);
    BGLD(bK0, 0, 0);
    STAGE_K(0, 1, 0);
    asm volatile("s_waitcnt vmcnt(2)" ::: "memory");
    SBAR();
    __builtin_amdgcn_s_barrier();
    SBAR();
    LDA4N(aP, 0, 0, 0);

    for (int T = 0; T < NT; ++T) {
        const int buf = T & 1, nbuf = buf ^ 1;
        int Tn = T + 1; if (Tn >= NT) Tn = 0;         // wrap: redundant loads, safe

        // ---- ph1: MFMA m0-3 k0; read A47k0(T); gld B_k1(T) ----
        LDA4N(aQ, buf, 0, 1);
        BGLD(bK1, T, 1);
        P_PRE();
        MFMA16(aP, bK0, 0);
        P_POSTC(4);                   // drains S1(T)
        // ---- ph2: MFMA m4-7 k0; read A03k1(T); stage S0(T+1) ----
        LDA4N(aP, buf, 1, 0);
        STAGE_K(nbuf, 0, Tn);
        P_PRE();
        MFMA16(aQ, bK0, 4);
        P_POSTC(2);                   // drains bK1(T)
        // ---- ph3: MFMA m0-3 k1; read A47k1(T); gld B_k0(T+1); stage S1(T+1) ----
        LDA4N(aQ, buf, 1, 1);
        BGLD(bK0, Tn, 0);
        STAGE_K(nbuf, 1, Tn);
        P_PRE();
        MFMA16(aP, bK1, 0);
        P_POSTC(6);                   // drains S0(T+1)
        // ---- ph4: MFMA m4-7 k1; read A03k0(T+1) from nbuf ----
        LDA4N(aP, nbuf, 0, 0);
        P_PRE();
        MFMA16(aQ, bK1, 4);
        P_POSTC(2);                   // drains bK0(T+1)
    }
    asm volatile("s_waitcnt vmcnt(0) lgkmcnt(0)" ::: "memory");
    SBAR();
    __builtin_amdgcn_s_barrier();     // LDS free for epilogue

    // epilogue: C/D layout col = lane&15, row = (lane>>4)*4 + j
    if (COLSUM == 0) {
        // LDS-bounce in two 128-row halves (64KB each)
        char* slb = (char*)lds;
        #pragma unroll
        for (int h = 0; h < 2; ++h) {
            if (wm == h) {
                #pragma unroll
                for (int nf = 0; nf < 4; ++nf) {
                    int col = wn * 64 + nf * 16 + (lane & 15);   // 0..255
                    float bv = bias[n0 + col];
                    #pragma unroll
                    for (int mf = 0; mf < 8; ++mf) {
                        int rb = mf * 16 + ((lane >> 4) << 2);   // 0..127 local
                        #pragma unroll
                        for (int j = 0; j < 4; ++j) {
                            int r = rb + j;
                            float v = fmaxf(acc[mf][nf][j] + bv, 0.f);
                            int byte = r * 512 + ((col * 2) ^ ((r & 7) << 4));
                            *(unsigned short*)(slb + byte) = f2bf_rne(v);
                        }
                    }
                }
            }
            __syncthreads();
            {
                int rsub = t >> 5;              // 0..15
                int cb = (t & 31) * 16;         // 0..496
                #pragma unroll
                for (int i2 = 0; i2 < 8; ++i2) {
                    int r = i2 * 16 + rsub;     // 0..127 local
                    const char* src = slb + r * 512 + (cb ^ ((r & 7) << 4));
                    uint32x4 v = *(const uint32x4*)src;
                    char* dst = (char*)Hout + ((size_t)(m0 + h * 128 + r) * HGDIM + n0) * 2 + cb;
                    *(uint32x4*)dst = v;
                }
            }
            __syncthreads();
        }
    } else {
        #pragma unroll
        for (int nf = 0; nf < 4; ++nf) {
            int ncol = n0 + wn * 64 + nf * 16 + (lane & 15);
            float bv = bias[ncol];
            float cs = 0.f;
            #pragma unroll
            for (int mf = 0; mf < 8; ++mf) {
                long rbase = row0g + m0 + wm * 128 + mf * 16 + ((lane >> 4) << 2);
                #pragma unroll
                for (int j = 0; j < 4; ++j) {
                    float v = fmaxf(acc[mf][nf][j] + bv, 0.f);
                    if (rbase + j < nvalid) cs += v;
                }
            }
            cs += __shfl_xor(cs, 16);
            cs += __shfl_xor(cs, 32);
            if ((lane >> 4) == 0) atomicAdd(&emb[ncol], cs);
        }
    }
}

extern "C" void kernel_launch(void* const* d_in, const int* in_sizes, int n_in,
                              void* d_out, int out_size, void* d_ws, size_t ws_size,
                              hipStream_t stream) {
    const float* x   = (const float*)d_in[0];
    const float* q   = (const float*)d_in[1];
    const float* gW0 = (const float*)d_in[2];
    const float* gb0 = (const float*)d_in[3];
    const float* gW1 = (const float*)d_in[4];
    const float* gb1 = (const float*)d_in[5];
    const float* gW2 = (const float*)d_in[6];
    const float* gb2 = (const float*)d_in[7];
    const float* fW0 = (const float*)d_in[8];
    const float* fb0 = (const float*)d_in[9];
    const float* fW1 = (const float*)d_in[10];
    const float* fb1 = (const float*)d_in[11];
    const float* fW2 = (const float*)d_in[12];
    const float* fb2 = (const float*)d_in[13];
    float* out = (float*)d_out;

    char* ws = (char*)d_ws;
    size_t off = 0;
    auto alloc = [&](size_t bytes) -> char* {
        char* p = ws + off;
        off += (bytes + 255) & ~(size_t)255;
        return p;
    };
    unsigned short* xb  = (unsigned short*)alloc((NROWS + 1) * 256 * 2);  // +1 zero row
    unsigned short* w0t = (unsigned short*)alloc((size_t)1024 * 512 * 2);
    unsigned short* w1t = (unsigned short*)alloc((size_t)1024 * 1024 * 2);
    unsigned short* w2t = (unsigned short*)alloc((size_t)1024 * 1024 * 2);
    float* c0  = (float*)alloc(4096);
    float* emb = (float*)alloc(4096);
    float* e1  = (float*)alloc(4096);
    float* e2  = (float*)alloc(4096);
    size_t fixed = off;
    size_t avail = (ws_size > fixed) ? ws_size - fixed : 0;
    long CR = (long)((avail / 2) / (HGDIM * 2));
    CR = (CR / 512) * 512;              // keep mblocks even -> nwg % 8 == 0
    if (CR > NROWS) CR = NROWS;
    if (CR < 512) CR = 512;
    unsigned short* H0 = (unsigned short*)alloc((size_t)CR * HGDIM * 2);
    unsigned short* H1 = (unsigned short*)alloc((size_t)CR * HGDIM * 2);

    hipMemsetAsync(c0, 0, 4 * 4096, stream);
    hipMemsetAsync(out, 0, 256 * sizeof(float), stream);

    long ntot4 = (NROWS + 1) * 256 / 4;
    cvt_x<<<dim3((unsigned)((ntot4 + 255) / 256)), 256, 0, stream>>>(x, xb, NROWS * 256, ntot4);

    transpose_cvt<<<dim3(32, 16), 256, 0, stream>>>(gW0, w0t, 512, 1024);
    transpose_cvt<<<dim3(32, 32), 256, 0, stream>>>(gW1, w1t, 1024, 1024);
    transpose_cvt<<<dim3(32, 32), 256, 0, stream>>>(gW2, w2t, 1024, 1024);

    // c0 = q @ W0[512:768] + b0  (fp32)
    fc_partial<false><<<dim3(4, 2), 256, 0, stream>>>(q, gW0 + (size_t)512 * 1024, gb0, c0, 1024);

    for (long r0 = 0; r0 < NROWS; r0 += CR) {
        long rows = NROWS - r0; if (rows > CR) rows = CR;
        int mblocks = (int)(rows / 256);
        dim3 g((unsigned)(mblocks * 4));
        // H0 = relu(x[:-1]*W0a + x[1:]*W0b + c0): A rows are overlapping 512-windows of xb
        gemmQ<0><<<g, 512, 0, stream>>>(xb + r0 * 256, 256, w0t, 512, c0, 512,
                                        H0, nullptr, 0, 0, mblocks);
        gemmQ<0><<<g, 512, 0, stream>>>(H0, 1024, w1t, 1024, gb1, 1024,
                                        H1, nullptr, 0, 0, mblocks);
        gemmQ<1><<<g, 512, 0, stream>>>(H1, 1024, w2t, 1024, gb2, 1024,
                                        nullptr, emb, r0, NVALID, mblocks);
    }

    fc_partial<false><<<dim3(4, 8), 256, 0, stream>>>(emb, fW0, fb0, e1, 1024);
    fc_partial<true><<<dim3(2, 8), 256, 0, stream>>>(e1, fW1, fb1, e2, 512);
    fc_partial<true><<<dim3(1, 4), 256, 0, stream>>>(e2, fW2, fb2, out, 256);
}

// Round 10
// 573.543 us; speedup vs baseline: 4.3340x; 4.3340x over previous
//
#include <hip/hip_runtime.h>

typedef __attribute__((ext_vector_type(8))) short short8;
typedef __attribute__((ext_vector_type(4))) float floatx4;
typedef __attribute__((ext_vector_type(4))) unsigned int uint32x4;

#define NROWS 32768L          // padded row count (real pair rows = 32767)
#define NVALID 32767L
#define HGDIM 1024

__device__ __forceinline__ unsigned short f2bf_rne(float f) {
    union { float f; unsigned u; } v; v.f = f;
    unsigned r = v.u + 0x7fffu + ((v.u >> 16) & 1u);
    return (unsigned short)(r >> 16);
}

__device__ __forceinline__ void gload_lds16(const void* g, void* l) {
    __builtin_amdgcn_global_load_lds(
        (const __attribute__((address_space(1))) void*)g,
        (__attribute__((address_space(3))) void*)l,
        16, 0, 0);
}

// ================= fused prep: cvt_x + 3 weight transposes + c0 ==================
#define NB_CVT 8193
#define NB_T0  512
#define NB_T1  1024
#define NB_T2  1024

__global__ void prep(const float* __restrict__ x, unsigned short* __restrict__ xb,
                     const float* __restrict__ gW0, unsigned short* __restrict__ w0t,
                     const float* __restrict__ gW1, unsigned short* __restrict__ w1t,
                     const float* __restrict__ gW2, unsigned short* __restrict__ w2t,
                     const float* __restrict__ q, const float* __restrict__ gb0,
                     float* __restrict__ c0) {
    __shared__ float smem[1056];
    int b = blockIdx.x, tid = threadIdx.x;
    if (b < NB_CVT) {
        long i = (long)b * 256 + tid;
        long ntot4 = (NROWS + 1) * 64;
        if (i < ntot4) {
            long i4 = i * 4, nx = NROWS * 256;
            float4 v = make_float4(0.f, 0.f, 0.f, 0.f);
            if (i4 < nx) v = *(const float4*)(x + i4);
            ushort4 o;
            o.x = f2bf_rne(v.x); o.y = f2bf_rne(v.y);
            o.z = f2bf_rne(v.z); o.w = f2bf_rne(v.w);
            *(ushort4*)(xb + i4) = o;
        }
        return;
    }
    b -= NB_CVT;
    const float* W; unsigned short* Wt; int K, N;
    if (b < NB_T0)                  { W = gW0; Wt = w0t; K = 512;  N = 1024; }
    else if (b < NB_T0 + NB_T1)     { b -= NB_T0; W = gW1; Wt = w1t; K = 1024; N = 1024; }
    else if (b < NB_T0 + NB_T1 + NB_T2) { b -= NB_T0 + NB_T1; W = gW2; Wt = w2t; K = 1024; N = 1024; }
    else {
        // c0 = q @ gW0[512:768] + gb0  (8 blocks: 4 j x 2 k)
        b -= NB_T0 + NB_T1 + NB_T2;
        int bx = b & 3, by = b >> 2;
        int j = bx * 256 + tid, k0 = by * 128;
        if (tid < 128) smem[tid] = q[k0 + tid];
        __syncthreads();
        float a = (by == 0) ? gb0[j] : 0.f;
        #pragma unroll 4
        for (int k = 0; k < 128; ++k)
            a += smem[k] * gW0[(size_t)(512 + k0 + k) * 1024 + j];
        atomicAdd(&c0[j], a);
        return;
    }
    int bx = b & 31, by = b >> 5;
    float (*tile)[33] = (float(*)[33])smem;
    int tx = tid & 31, ty = tid >> 5;
    int nb2 = bx * 32, kb = by * 32;
    #pragma unroll
    for (int i = 0; i < 32; i += 8)
        tile[ty + i][tx] = W[(size_t)(kb + ty + i) * N + (nb2 + tx)];
    __syncthreads();
    #pragma unroll
    for (int i = 0; i < 32; i += 8)
        Wt[(size_t)(nb2 + ty + i) * K + (kb + tx)] = f2bf_rne(tile[tx][ty + i]);
}

// ================= fused f-MLP: one block, 512 threads ===========================
__global__ void fmlp(const float* __restrict__ emb,
                     const float* __restrict__ fW0, const float* __restrict__ fb0,
                     const float* __restrict__ fW1, const float* __restrict__ fb1,
                     const float* __restrict__ fW2, const float* __restrict__ fb2,
                     float* __restrict__ out) {
    __shared__ float s0[1024];
    __shared__ float s1[1024];
    int tid = threadIdx.x;
    for (int i = tid; i < 1024; i += 512) s0[i] = emb[i];
    __syncthreads();
    for (int j = tid; j < 1024; j += 512) {
        float a = fb0[j];
        #pragma unroll 4
        for (int k = 0; k < 1024; ++k) a += s0[k] * fW0[(size_t)k * 1024 + j];
        s1[j] = fmaxf(a, 0.f);
    }
    __syncthreads();
    if (tid < 512) {
        float a = fb1[tid];
        #pragma unroll 4
        for (int k = 0; k < 1024; ++k) a += s1[k] * fW1[(size_t)k * 512 + tid];
        s0[tid] = fmaxf(a, 0.f);
    }
    __syncthreads();
    if (tid < 256) {
        float a = fb2[tid];
        #pragma unroll 4
        for (int k = 0; k < 512; ++k) a += s0[k] * fW2[(size_t)k * 256 + tid];
        out[tid] = a;
    }
}

// ================== 256x256 bf16 MFMA GEMM: A-only LDS (64KB), B direct L2 =======
// 8 phases / 2 K-tiles; per phase: 4 ds_reads, <=1 A-stage pair, <=1 B-gld quad,
// barrier, counted lgkm(4), 16 MFMA, counted vmcnt ladder (8/4/0), barrier.
// C(m,n) = A(m x K) * Bt(n x K)^T.  COLSUM=0: Hout=relu(C+bias), LDS-bounce.
// COLSUM=1: masked column-sum of relu(C+bias) atomicAdd into emb.

#define SBAR() __builtin_amdgcn_sched_barrier(0)

#define R_PRE() do { SBAR(); __builtin_amdgcn_s_barrier(); \
    asm volatile("s_waitcnt lgkmcnt(4)" ::: "memory"); SBAR(); \
    __builtin_amdgcn_s_setprio(1); } while (0)

#define R_POST() do { __builtin_amdgcn_s_setprio(0); SBAR(); \
    __builtin_amdgcn_s_barrier(); } while (0)

#define R_POSTV(N) do { __builtin_amdgcn_s_setprio(0); SBAR(); \
    asm volatile("s_waitcnt vmcnt(" #N ")" ::: "memory"); SBAR(); \
    __builtin_amdgcn_s_barrier(); SBAR(); } while (0)

// stage one 128-row x 64-col A half (16KB) of K-tile T into buf
#define STAGE_A(buf, half, T) do { \
    const unsigned short* _g = gAs + (size_t)((half) * 128) * lda + (size_t)(T) * 64; \
    char* _d = (char*)&lds[buf][(half) * 128][0] + t * 16; \
    gload_lds16(_g, _d); \
    gload_lds16(_g + (size_t)64 * lda, _d + 8192); } while (0)

#define LDA4(dst, buf, mbase, ks) do { _Pragma("unroll") for (int _q = 0; _q < 4; ++_q) \
    dst[_q] = *(const short8*)((const char*)&lds[buf][arowb + ((mbase) + _q) * 16][0] + ((ks) ? cb1 : cb0)); } while (0)

// load one B fragment quad (4 n-subtiles) direct from global (L2/L3-hot)
#define BGLD(dst, T, kk) do { _Pragma("unroll") for (int _nf = 0; _nf < 4; ++_nf) \
    dst[_nf] = *(const short8*)(bBase + (size_t)_nf * 16 * ldb + (size_t)(T) * 64 + (kk) * 32); } while (0)

#define MFMA16(AF, BF, MO) do { _Pragma("unroll") for (int _mf = 0; _mf < 4; ++_mf) { \
    _Pragma("unroll") for (int _nf = 0; _nf < 4; ++_nf) \
        acc[(MO) + _mf][_nf] = __builtin_amdgcn_mfma_f32_16x16x32_bf16(AF[_mf], BF[_nf], acc[(MO) + _mf][_nf], 0, 0, 0); } } while (0)

template<int COLSUM>
__global__ __launch_bounds__(512, 2)
void gemmR(const unsigned short* __restrict__ A, int lda,
           const unsigned short* __restrict__ Bt, int ldb,
           const float* __restrict__ bias, int K,
           unsigned short* __restrict__ Hout,
           float* __restrict__ emb, long row0g, long nvalid,
           int mblocks) {
    __shared__ alignas(16) unsigned short lds[2][256][64];   // A only, 64 KiB

    const int t = threadIdx.x;        // 0..511
    // XCD-aware swizzle (bijective since nwg % 8 == 0); n-fastest within chunk
    int nwg = gridDim.x, bid = blockIdx.x, swz;
    if ((nwg & 7) == 0) { int cpx = nwg >> 3; swz = (bid & 7) * cpx + (bid >> 3); }
    else swz = bid;
    const int mb = swz >> 2, nb = swz & 3;
    const long m0 = (long)mb * 256;
    const int n0 = nb * 256;

    const int lane = t & 63;
    const int wv = t >> 6;
    const int wm = wv >> 2, wn = wv & 3;              // 2 M-waves x 4 N-waves
    const int arowb = wm * 128 + (lane & 15);
    const int c0x = (lane >> 4) ^ (lane & 7);
    const int cb0 = c0x * 16;
    const int cb1 = (c0x ^ 4) * 16;
    // B direct-load base: row = n-col, k-chunk = (lane>>4)*8
    const unsigned short* bBase = Bt + (size_t)(n0 + wn * 64 + (lane & 15)) * ldb + ((lane >> 4) << 3);

    // A staging: thread t covers row t>>3 (within 64-row group), chunk t&7 (pre-swizzled)
    const int srow = t >> 3;
    const unsigned short* gAs = A + (size_t)(m0 + srow) * lda + (((t & 7) ^ (srow & 7)) << 3);

    floatx4 acc[8][4] = {};
    short8 aP[4], aQ[4], bE0[4], bE1[4], bO0[4], bO1[4];

    const int NT = K >> 6;            // even (8 or 16)
    const int NI = NT >> 1;

    // prologue: stage tile0 A (4 gloads); load bE0(T0,k0); prove all; first A read
    STAGE_A(0, 0, 0); STAGE_A(0, 1, 0);
    BGLD(bE0, 0, 0);
    asm volatile("s_waitcnt vmcnt(0)" ::: "memory");
    SBAR();
    __builtin_amdgcn_s_barrier();
    SBAR();
    LDA4(aP, 0, 0, 0);                // A03k0 tile0 (4 reads outstanding)

    for (int i = 0; i < NI; ++i) {
        const int T = 2 * i;
        int T1 = T + 1;
        int T2 = T + 2; if (T2 >= NT) T2 = 0;         // wrap: redundant loads, safe

        // ph1: T(buf0) m0-3 k0 | read A47k0(b0); gld bE1(T,k1); stage A0(T1->b1)
        LDA4(aQ, 0, 4, 0); BGLD(bE1, T, 1); STAGE_A(1, 0, T1);
        R_PRE(); MFMA16(aP, bE0, 0); R_POST();
        // ph2: m4-7 k0 | read A03k1(b0); stage A1(T1->b1); gld bO0(T1,k0)
        LDA4(aP, 0, 0, 1); STAGE_A(1, 1, T1); BGLD(bO0, T1, 0);
        R_PRE(); MFMA16(aQ, bE0, 4); R_POSTV(8);      // proves bE1
        // ph3: m0-3 k1 | read A47k1(b0)
        LDA4(aQ, 0, 4, 1);
        R_PRE(); MFMA16(aP, bE1, 0); R_POSTV(4);      // proves A(T1) stages
        // ph4: m4-7 k1 | read A03k0(b1) [tile T1]
        LDA4(aP, 1, 0, 0);
        R_PRE(); MFMA16(aQ, bE1, 4); R_POSTV(0);      // proves bO0 (2 phases old, L2)
        // ph5: T1(buf1) m0-3 k0 | read A47k0(b1); gld bO1(T1,k1); stage A0(T2->b0)
        LDA4(aQ, 1, 4, 0); BGLD(bO1, T1, 1); STAGE_A(0, 0, T2);
        R_PRE(); MFMA16(aP, bO0, 0); R_POST();
        // ph6: m4-7 k0 | read A03k1(b1); stage A1(T2->b0); gld bE0(T2,k0)
        LDA4(aP, 1, 0, 1); STAGE_A(0, 1, T2); BGLD(bE0, T2, 0);
        R_PRE(); MFMA16(aQ, bO0, 4); R_POSTV(8);      // proves bO1
        // ph7: m0-3 k1 | read A47k1(b1)
        LDA4(aQ, 1, 4, 1);
        R_PRE(); MFMA16(aP, bO1, 0); R_POSTV(4);      // proves A(T2) stages
        // ph8: m4-7 k1 | read A03k0(b0) [tile T2]
        LDA4(aP, 0, 0, 0);
        R_PRE(); MFMA16(aQ, bO1, 4); R_POSTV(0);      // proves bE0(T2)
    }
    asm volatile("s_waitcnt vmcnt(0) lgkmcnt(0)" ::: "memory");
    SBAR();
    __builtin_amdgcn_s_barrier();     // LDS free for epilogue

    // epilogue: C/D layout col = lane&15, row = (lane>>4)*4 + j
    if (COLSUM == 0) {
        // LDS-bounce in two 128-row halves (64KB each)
        char* slb = (char*)lds;
        #pragma unroll
        for (int h = 0; h < 2; ++h) {
            if (wm == h) {
                #pragma unroll
                for (int nf = 0; nf < 4; ++nf) {
                    int col = wn * 64 + nf * 16 + (lane & 15);   // 0..255
                    float bv = bias[n0 + col];
                    #pragma unroll
                    for (int mf = 0; mf < 8; ++mf) {
                        int rb = mf * 16 + ((lane >> 4) << 2);   // 0..127 local
                        #pragma unroll
                        for (int j = 0; j < 4; ++j) {
                            int r = rb + j;
                            float v = fmaxf(acc[mf][nf][j] + bv, 0.f);
                            int byte = r * 512 + ((col * 2) ^ ((r & 7) << 4));
                            *(unsigned short*)(slb + byte) = f2bf_rne(v);
                        }
                    }
                }
            }
            __syncthreads();
            {
                int rsub = t >> 5;              // 0..15
                int cb = (t & 31) * 16;         // 0..496
                #pragma unroll
                for (int i2 = 0; i2 < 8; ++i2) {
                    int r = i2 * 16 + rsub;     // 0..127 local
                    const char* src = slb + r * 512 + (cb ^ ((r & 7) << 4));
                    uint32x4 v = *(const uint32x4*)src;
                    char* dst = (char*)Hout + ((size_t)(m0 + h * 128 + r) * HGDIM + n0) * 2 + cb;
                    *(uint32x4*)dst = v;
                }
            }
            __syncthreads();
        }
    } else {
        #pragma unroll
        for (int nf = 0; nf < 4; ++nf) {
            int ncol = n0 + wn * 64 + nf * 16 + (lane & 15);
            float bv = bias[ncol];
            float cs = 0.f;
            #pragma unroll
            for (int mf = 0; mf < 8; ++mf) {
                long rbase = row0g + m0 + wm * 128 + mf * 16 + ((lane >> 4) << 2);
                #pragma unroll
                for (int j = 0; j < 4; ++j) {
                    float v = fmaxf(acc[mf][nf][j] + bv, 0.f);
                    if (rbase + j < nvalid) cs += v;
                }
            }
            cs += __shfl_xor(cs, 16);
            cs += __shfl_xor(cs, 32);
            if ((lane >> 4) == 0) atomicAdd(&emb[ncol], cs);
        }
    }
}

extern "C" void kernel_launch(void* const* d_in, const int* in_sizes, int n_in,
                              void* d_out, int out_size, void* d_ws, size_t ws_size,
                              hipStream_t stream) {
    const float* x   = (const float*)d_in[0];
    const float* q   = (const float*)d_in[1];
    const float* gW0 = (const float*)d_in[2];
    const float* gb0 = (const float*)d_in[3];
    const float* gW1 = (const float*)d_in[4];
    const float* gb1 = (const float*)d_in[5];
    const float* gW2 = (const float*)d_in[6];
    const float* gb2 = (const float*)d_in[7];
    const float* fW0 = (const float*)d_in[8];
    const float* fb0 = (const float*)d_in[9];
    const float* fW1 = (const float*)d_in[10];
    const float* fb1 = (const float*)d_in[11];
    const float* fW2 = (const float*)d_in[12];
    const float* fb2 = (const float*)d_in[13];
    float* out = (float*)d_out;

    char* ws = (char*)d_ws;
    size_t off = 0;
    auto alloc = [&](size_t bytes) -> char* {
        char* p = ws + off;
        off += (bytes + 255) & ~(size_t)255;
        return p;
    };
    unsigned short* xb  = (unsigned short*)alloc((NROWS + 1) * 256 * 2);  // +1 zero row
    unsigned short* w0t = (unsigned short*)alloc((size_t)1024 * 512 * 2);
    unsigned short* w1t = (unsigned short*)alloc((size_t)1024 * 1024 * 2);
    unsigned short* w2t = (unsigned short*)alloc((size_t)1024 * 1024 * 2);
    float* c0  = (float*)alloc(4096);
    float* emb = (float*)alloc(4096);   // contiguous after c0
    size_t fixed = off;
    size_t avail = (ws_size > fixed) ? ws_size - fixed : 0;
    long CR = (long)((avail / 2) / (HGDIM * 2));
    CR = (CR / 512) * 512;              // keep mblocks even -> nwg % 8 == 0
    if (CR > NROWS) CR = NROWS;
    if (CR < 512) CR = 512;
    unsigned short* H0 = (unsigned short*)alloc((size_t)CR * HGDIM * 2);
    unsigned short* H1 = (unsigned short*)alloc((size_t)CR * HGDIM * 2);

    hipMemsetAsync(c0, 0, 8192, stream);   // c0 + emb

    prep<<<dim3(NB_CVT + NB_T0 + NB_T1 + NB_T2 + 8), 256, 0, stream>>>(
        x, xb, gW0, w0t, gW1, w1t, gW2, w2t, q, gb0, c0);

    for (long r0 = 0; r0 < NROWS; r0 += CR) {
        long rows = NROWS - r0; if (rows > CR) rows = CR;
        int mblocks = (int)(rows / 256);
        dim3 g((unsigned)(mblocks * 4));
        // H0 = relu(x[:-1]*W0a + x[1:]*W0b + c0): A rows are overlapping 512-windows of xb
        gemmR<0><<<g, 512, 0, stream>>>(xb + r0 * 256, 256, w0t, 512, c0, 512,
                                        H0, nullptr, 0, 0, mblocks);
        gemmR<0><<<g, 512, 0, stream>>>(H0, 1024, w1t, 1024, gb1, 1024,
                                        H1, nullptr, 0, 0, mblocks);
        gemmR<1><<<g, 512, 0, stream>>>(H1, 1024, w2t, 1024, gb2, 1024,
                                        nullptr, emb, r0, NVALID, mblocks);
    }

    fmlp<<<dim3(1), 512, 0, stream>>>(emb, fW0, fb0, fW1, fb1, fW2, fb2, out);
}

// Round 11
// 322.139 us; speedup vs baseline: 7.7164x; 1.7804x over previous
//
#include <hip/hip_runtime.h>

typedef __attribute__((ext_vector_type(8))) short short8;
typedef __attribute__((ext_vector_type(4))) float floatx4;
typedef __attribute__((ext_vector_type(4))) unsigned int uint32x4;

#define NROWS 32768L          // padded row count (real pair rows = 32767)
#define NVALID 32767L
#define HGDIM 1024

__device__ __forceinline__ unsigned short f2bf_rne(float f) {
    union { float f; unsigned u; } v; v.f = f;
    unsigned r = v.u + 0x7fffu + ((v.u >> 16) & 1u);
    return (unsigned short)(r >> 16);
}

__device__ __forceinline__ void gload_lds16(const void* g, void* l) {
    __builtin_amdgcn_global_load_lds(
        (const __attribute__((address_space(1))) void*)g,
        (__attribute__((address_space(3))) void*)l,
        16, 0, 0);
}

// ================= fused prep: cvt_x + 3 weight transposes + c0 ==================
#define NB_CVT 8193
#define NB_T0  512
#define NB_T1  1024
#define NB_T2  1024

__global__ void prep(const float* __restrict__ x, unsigned short* __restrict__ xb,
                     const float* __restrict__ gW0, unsigned short* __restrict__ w0t,
                     const float* __restrict__ gW1, unsigned short* __restrict__ w1t,
                     const float* __restrict__ gW2, unsigned short* __restrict__ w2t,
                     const float* __restrict__ q, const float* __restrict__ gb0,
                     float* __restrict__ c0) {
    __shared__ float smem[1056];
    int b = blockIdx.x, tid = threadIdx.x;
    if (b < NB_CVT) {
        long i = (long)b * 256 + tid;
        long ntot4 = (NROWS + 1) * 64;
        if (i < ntot4) {
            long i4 = i * 4, nx = NROWS * 256;
            float4 v = make_float4(0.f, 0.f, 0.f, 0.f);
            if (i4 < nx) v = *(const float4*)(x + i4);
            ushort4 o;
            o.x = f2bf_rne(v.x); o.y = f2bf_rne(v.y);
            o.z = f2bf_rne(v.z); o.w = f2bf_rne(v.w);
            *(ushort4*)(xb + i4) = o;
        }
        return;
    }
    b -= NB_CVT;
    const float* W; unsigned short* Wt; int K, N;
    if (b < NB_T0)                  { W = gW0; Wt = w0t; K = 512;  N = 1024; }
    else if (b < NB_T0 + NB_T1)     { b -= NB_T0; W = gW1; Wt = w1t; K = 1024; N = 1024; }
    else if (b < NB_T0 + NB_T1 + NB_T2) { b -= NB_T0 + NB_T1; W = gW2; Wt = w2t; K = 1024; N = 1024; }
    else {
        // c0 = q @ gW0[512:768] + gb0  (8 blocks: 4 j x 2 k)
        b -= NB_T0 + NB_T1 + NB_T2;
        int bx = b & 3, by = b >> 2;
        int j = bx * 256 + tid, k0 = by * 128;
        if (tid < 128) smem[tid] = q[k0 + tid];
        __syncthreads();
        float a = (by == 0) ? gb0[j] : 0.f;
        #pragma unroll 4
        for (int k = 0; k < 128; ++k)
            a += smem[k] * gW0[(size_t)(512 + k0 + k) * 1024 + j];
        atomicAdd(&c0[j], a);
        return;
    }
    int bx = b & 31, by = b >> 5;
    float (*tile)[33] = (float(*)[33])smem;
    int tx = tid & 31, ty = tid >> 5;
    int nb2 = bx * 32, kb = by * 32;
    #pragma unroll
    for (int i = 0; i < 32; i += 8)
        tile[ty + i][tx] = W[(size_t)(kb + ty + i) * N + (nb2 + tx)];
    __syncthreads();
    #pragma unroll
    for (int i = 0; i < 32; i += 8)
        Wt[(size_t)(nb2 + ty + i) * K + (kb + tx)] = f2bf_rne(tile[tx][ty + i]);
}

// ---- small fp32 FC partial (multi-block, atomic K-split) ----
template<bool RELU_IN>
__global__ void fc_partial(const float* __restrict__ in, const float* __restrict__ W,
                           const float* __restrict__ bias, float* __restrict__ out,
                           int N) {
    __shared__ float s_in[128];
    int j = blockIdx.x * 256 + threadIdx.x;
    int k0 = blockIdx.y * 128;
    if (threadIdx.x < 128) {
        float v = in[k0 + threadIdx.x];
        if (RELU_IN) v = fmaxf(v, 0.f);
        s_in[threadIdx.x] = v;
    }
    __syncthreads();
    float acc = (blockIdx.y == 0) ? bias[j] : 0.f;
    #pragma unroll 4
    for (int k = 0; k < 128; ++k)
        acc += s_in[k] * W[(size_t)(k0 + k) * N + j];
    atomicAdd(&out[j], acc);
}

// ================== 256x256 bf16 MFMA GEMM: A-only LDS (64KB), B direct L2 =======
// 8 phases / 2 K-tiles; per phase: 4 ds_reads, <=1 A-stage pair, <=1 B-gld quad,
// barrier, counted lgkm(4), 16 MFMA, counted vmcnt ladder (8/4/0), barrier.
// C(m,n) = A(m x K) * Bt(n x K)^T.  COLSUM=0: Hout=relu(C+bias), LDS-bounce.
// COLSUM=1: masked column-sum of relu(C+bias) atomicAdd into emb.

#define SBAR() __builtin_amdgcn_sched_barrier(0)

#define R_PRE() do { SBAR(); __builtin_amdgcn_s_barrier(); \
    asm volatile("s_waitcnt lgkmcnt(4)" ::: "memory"); SBAR(); \
    __builtin_amdgcn_s_setprio(1); } while (0)

#define R_POST() do { __builtin_amdgcn_s_setprio(0); SBAR(); \
    __builtin_amdgcn_s_barrier(); } while (0)

#define R_POSTV(N) do { __builtin_amdgcn_s_setprio(0); SBAR(); \
    asm volatile("s_waitcnt vmcnt(" #N ")" ::: "memory"); SBAR(); \
    __builtin_amdgcn_s_barrier(); SBAR(); } while (0)

// stage one 128-row x 64-col A half (16KB) of K-tile T into buf
#define STAGE_A(buf, half, T) do { \
    const unsigned short* _g = gAs + (size_t)((half) * 128) * lda + (size_t)(T) * 64; \
    char* _d = (char*)&lds[buf][(half) * 128][0] + t * 16; \
    gload_lds16(_g, _d); \
    gload_lds16(_g + (size_t)64 * lda, _d + 8192); } while (0)

#define LDA4(dst, buf, mbase, ks) do { _Pragma("unroll") for (int _q = 0; _q < 4; ++_q) \
    dst[_q] = *(const short8*)((const char*)&lds[buf][arowb + ((mbase) + _q) * 16][0] + ((ks) ? cb1 : cb0)); } while (0)

// load one B fragment quad (4 n-subtiles) direct from global (L2/L3-hot)
#define BGLD(dst, T, kk) do { _Pragma("unroll") for (int _nf = 0; _nf < 4; ++_nf) \
    dst[_nf] = *(const short8*)(bBase + (size_t)_nf * 16 * ldb + (size_t)(T) * 64 + (kk) * 32); } while (0)

#define MFMA16(AF, BF, MO) do { _Pragma("unroll") for (int _mf = 0; _mf < 4; ++_mf) { \
    _Pragma("unroll") for (int _nf = 0; _nf < 4; ++_nf) \
        acc[(MO) + _mf][_nf] = __builtin_amdgcn_mfma_f32_16x16x32_bf16(AF[_mf], BF[_nf], acc[(MO) + _mf][_nf], 0, 0, 0); } } while (0)

template<int COLSUM>
__global__ __launch_bounds__(512, 2)
void gemmR(const unsigned short* __restrict__ A, int lda,
           const unsigned short* __restrict__ Bt, int ldb,
           const float* __restrict__ bias, int K,
           unsigned short* __restrict__ Hout,
           float* __restrict__ emb, long row0g, long nvalid,
           int mblocks) {
    __shared__ alignas(16) unsigned short lds[2][256][64];   // A only, 64 KiB

    const int t = threadIdx.x;        // 0..511
    // XCD-aware swizzle (bijective since nwg % 8 == 0); n-fastest within chunk
    int nwg = gridDim.x, bid = blockIdx.x, swz;
    if ((nwg & 7) == 0) { int cpx = nwg >> 3; swz = (bid & 7) * cpx + (bid >> 3); }
    else swz = bid;
    const int mb = swz >> 2, nb = swz & 3;
    const long m0 = (long)mb * 256;
    const int n0 = nb * 256;

    const int lane = t & 63;
    const int wv = t >> 6;
    const int wm = wv >> 2, wn = wv & 3;              // 2 M-waves x 4 N-waves
    const int arowb = wm * 128 + (lane & 15);
    const int c0x = (lane >> 4) ^ (lane & 7);
    const int cb0 = c0x * 16;
    const int cb1 = (c0x ^ 4) * 16;
    // B direct-load base: row = n-col, k-chunk = (lane>>4)*8
    const unsigned short* bBase = Bt + (size_t)(n0 + wn * 64 + (lane & 15)) * ldb + ((lane >> 4) << 3);

    // A staging: thread t covers row t>>3 (within 64-row group), chunk t&7 (pre-swizzled)
    const int srow = t >> 3;
    const unsigned short* gAs = A + (size_t)(m0 + srow) * lda + (((t & 7) ^ (srow & 7)) << 3);

    floatx4 acc[8][4] = {};
    short8 aP[4], aQ[4], bE0[4], bE1[4], bO0[4], bO1[4];

    const int NT = K >> 6;            // even (8 or 16)
    const int NI = NT >> 1;

    // prologue: stage tile0 A (4 gloads); load bE0(T0,k0); prove all; first A read
    STAGE_A(0, 0, 0); STAGE_A(0, 1, 0);
    BGLD(bE0, 0, 0);
    asm volatile("s_waitcnt vmcnt(0)" ::: "memory");
    SBAR();
    __builtin_amdgcn_s_barrier();
    SBAR();
    LDA4(aP, 0, 0, 0);                // A03k0 tile0 (4 reads outstanding)

    for (int i = 0; i < NI; ++i) {
        const int T = 2 * i;
        int T1 = T + 1;
        int T2 = T + 2; if (T2 >= NT) T2 = 0;         // wrap: redundant loads, safe

        // ph1: T(buf0) m0-3 k0 | read A47k0(b0); gld bE1(T,k1); stage A0(T1->b1)
        LDA4(aQ, 0, 4, 0); BGLD(bE1, T, 1); STAGE_A(1, 0, T1);
        R_PRE(); MFMA16(aP, bE0, 0); R_POST();
        // ph2: m4-7 k0 | read A03k1(b0); stage A1(T1->b1); gld bO0(T1,k0)
        LDA4(aP, 0, 0, 1); STAGE_A(1, 1, T1); BGLD(bO0, T1, 0);
        R_PRE(); MFMA16(aQ, bE0, 4); R_POSTV(8);      // proves bE1
        // ph3: m0-3 k1 | read A47k1(b0)
        LDA4(aQ, 0, 4, 1);
        R_PRE(); MFMA16(aP, bE1, 0); R_POSTV(4);      // proves A(T1) stages
        // ph4: m4-7 k1 | read A03k0(b1) [tile T1]
        LDA4(aP, 1, 0, 0);
        R_PRE(); MFMA16(aQ, bE1, 4); R_POSTV(0);      // proves bO0 (2 phases old, L2)
        // ph5: T1(buf1) m0-3 k0 | read A47k0(b1); gld bO1(T1,k1); stage A0(T2->b0)
        LDA4(aQ, 1, 4, 0); BGLD(bO1, T1, 1); STAGE_A(0, 0, T2);
        R_PRE(); MFMA16(aP, bO0, 0); R_POST();
        // ph6: m4-7 k0 | read A03k1(b1); stage A1(T2->b0); gld bE0(T2,k0)
        LDA4(aP, 1, 0, 1); STAGE_A(0, 1, T2); BGLD(bE0, T2, 0);
        R_PRE(); MFMA16(aQ, bO0, 4); R_POSTV(8);      // proves bO1
        // ph7: m0-3 k1 | read A47k1(b1)
        LDA4(aQ, 1, 4, 1);
        R_PRE(); MFMA16(aP, bO1, 0); R_POSTV(4);      // proves A(T2) stages
        // ph8: m4-7 k1 | read A03k0(b0) [tile T2]
        LDA4(aP, 0, 0, 0);
        R_PRE(); MFMA16(aQ, bO1, 4); R_POSTV(0);      // proves bE0(T2)
    }
    asm volatile("s_waitcnt vmcnt(0) lgkmcnt(0)" ::: "memory");
    SBAR();
    __builtin_amdgcn_s_barrier();     // LDS free for epilogue

    // epilogue: C/D layout col = lane&15, row = (lane>>4)*4 + j
    if (COLSUM == 0) {
        // LDS-bounce in two 128-row halves (64KB each)
        char* slb = (char*)lds;
        #pragma unroll
        for (int h = 0; h < 2; ++h) {
            if (wm == h) {
                #pragma unroll
                for (int nf = 0; nf < 4; ++nf) {
                    int col = wn * 64 + nf * 16 + (lane & 15);   // 0..255
                    float bv = bias[n0 + col];
                    #pragma unroll
                    for (int mf = 0; mf < 8; ++mf) {
                        int rb = mf * 16 + ((lane >> 4) << 2);   // 0..127 local
                        #pragma unroll
                        for (int j = 0; j < 4; ++j) {
                            int r = rb + j;
                            float v = fmaxf(acc[mf][nf][j] + bv, 0.f);
                            int byte = r * 512 + ((col * 2) ^ ((r & 7) << 4));
                            *(unsigned short*)(slb + byte) = f2bf_rne(v);
                        }
                    }
                }
            }
            __syncthreads();
            {
                int rsub = t >> 5;              // 0..15
                int cb = (t & 31) * 16;         // 0..496
                #pragma unroll
                for (int i2 = 0; i2 < 8; ++i2) {
                    int r = i2 * 16 + rsub;     // 0..127 local
                    const char* src = slb + r * 512 + (cb ^ ((r & 7) << 4));
                    uint32x4 v = *(const uint32x4*)src;
                    char* dst = (char*)Hout + ((size_t)(m0 + h * 128 + r) * HGDIM + n0) * 2 + cb;
                    *(uint32x4*)dst = v;
                }
            }
            __syncthreads();
        }
    } else {
        #pragma unroll
        for (int nf = 0; nf < 4; ++nf) {
            int ncol = n0 + wn * 64 + nf * 16 + (lane & 15);
            float bv = bias[ncol];
            float cs = 0.f;
            #pragma unroll
            for (int mf = 0; mf < 8; ++mf) {
                long rbase = row0g + m0 + wm * 128 + mf * 16 + ((lane >> 4) << 2);
                #pragma unroll
                for (int j = 0; j < 4; ++j) {
                    float v = fmaxf(acc[mf][nf][j] + bv, 0.f);
                    if (rbase + j < nvalid) cs += v;
                }
            }
            cs += __shfl_xor(cs, 16);
            cs += __shfl_xor(cs, 32);
            if ((lane >> 4) == 0) atomicAdd(&emb[ncol], cs);
        }
    }
}

extern "C" void kernel_launch(void* const* d_in, const int* in_sizes, int n_in,
                              void* d_out, int out_size, void* d_ws, size_t ws_size,
                              hipStream_t stream) {
    const float* x   = (const float*)d_in[0];
    const float* q   = (const float*)d_in[1];
    const float* gW0 = (const float*)d_in[2];
    const float* gb0 = (const float*)d_in[3];
    const float* gW1 = (const float*)d_in[4];
    const float* gb1 = (const float*)d_in[5];
    const float* gW2 = (const float*)d_in[6];
    const float* gb2 = (const float*)d_in[7];
    const float* fW0 = (const float*)d_in[8];
    const float* fb0 = (const float*)d_in[9];
    const float* fW1 = (const float*)d_in[10];
    const float* fb1 = (const float*)d_in[11];
    const float* fW2 = (const float*)d_in[12];
    const float* fb2 = (const float*)d_in[13];
    float* out = (float*)d_out;

    char* ws = (char*)d_ws;
    size_t off = 0;
    auto alloc = [&](size_t bytes) -> char* {
        char* p = ws + off;
        off += (bytes + 255) & ~(size_t)255;
        return p;
    };
    unsigned short* xb  = (unsigned short*)alloc((NROWS + 1) * 256 * 2);  // +1 zero row
    unsigned short* w0t = (unsigned short*)alloc((size_t)1024 * 512 * 2);
    unsigned short* w1t = (unsigned short*)alloc((size_t)1024 * 1024 * 2);
    unsigned short* w2t = (unsigned short*)alloc((size_t)1024 * 1024 * 2);
    float* c0  = (float*)alloc(4096);
    float* emb = (float*)alloc(4096);
    float* e1  = (float*)alloc(4096);
    float* e2  = (float*)alloc(4096);
    size_t fixed = off;
    size_t avail = (ws_size > fixed) ? ws_size - fixed : 0;
    long CR = (long)((avail / 2) / (HGDIM * 2));
    CR = (CR / 512) * 512;              // keep mblocks even -> nwg % 8 == 0
    if (CR > NROWS) CR = NROWS;
    if (CR < 512) CR = 512;
    unsigned short* H0 = (unsigned short*)alloc((size_t)CR * HGDIM * 2);
    unsigned short* H1 = (unsigned short*)alloc((size_t)CR * HGDIM * 2);

    hipMemsetAsync(c0, 0, 4 * 4096, stream);   // c0 + emb + e1 + e2
    hipMemsetAsync(out, 0, 256 * sizeof(float), stream);

    prep<<<dim3(NB_CVT + NB_T0 + NB_T1 + NB_T2 + 8), 256, 0, stream>>>(
        x, xb, gW0, w0t, gW1, w1t, gW2, w2t, q, gb0, c0);

    for (long r0 = 0; r0 < NROWS; r0 += CR) {
        long rows = NROWS - r0; if (rows > CR) rows = CR;
        int mblocks = (int)(rows / 256);
        dim3 g((unsigned)(mblocks * 4));
        // H0 = relu(x[:-1]*W0a + x[1:]*W0b + c0): A rows are overlapping 512-windows of xb
        gemmR<0><<<g, 512, 0, stream>>>(xb + r0 * 256, 256, w0t, 512, c0, 512,
                                        H0, nullptr, 0, 0, mblocks);
        gemmR<0><<<g, 512, 0, stream>>>(H0, 1024, w1t, 1024, gb1, 1024,
                                        H1, nullptr, 0, 0, mblocks);
        gemmR<1><<<g, 512, 0, stream>>>(H1, 1024, w2t, 1024, gb2, 1024,
                                        nullptr, emb, r0, NVALID, mblocks);
    }

    fc_partial<false><<<dim3(4, 8), 256, 0, stream>>>(emb, fW0, fb0, e1, 1024);
    fc_partial<true><<<dim3(2, 8), 256, 0, stream>>>(e1, fW1, fb1, e2, 512);
    fc_partial<true><<<dim3(1, 4), 256, 0, stream>>>(e2, fW2, fb2, out, 256);
}

// Round 12
// 231.036 us; speedup vs baseline: 10.7591x; 1.3943x over previous
//
#include <hip/hip_runtime.h>

typedef __attribute__((ext_vector_type(8))) short short8;
typedef __attribute__((ext_vector_type(4))) float floatx4;
typedef __attribute__((ext_vector_type(4))) unsigned int uint32x4;

#define NROWS 32768L          // padded row count (real pair rows = 32767)
#define NVALID 32767L
#define HGDIM 1024

__device__ __forceinline__ unsigned short f2bf_rne(float f) {
    union { float f; unsigned u; } v; v.f = f;
    unsigned r = v.u + 0x7fffu + ((v.u >> 16) & 1u);
    return (unsigned short)(r >> 16);
}

__device__ __forceinline__ void gload_lds16(const void* g, void* l) {
    __builtin_amdgcn_global_load_lds(
        (const __attribute__((address_space(1))) void*)g,
        (__attribute__((address_space(3))) void*)l,
        16, 0, 0);
}

// ================= fused prep: cvt_x + 3 weight transposes + c0 ==================
#define NB_CVT 8193
#define NB_T0  512
#define NB_T1  1024
#define NB_T2  1024

__global__ void prep(const float* __restrict__ x, unsigned short* __restrict__ xb,
                     const float* __restrict__ gW0, unsigned short* __restrict__ w0t,
                     const float* __restrict__ gW1, unsigned short* __restrict__ w1t,
                     const float* __restrict__ gW2, unsigned short* __restrict__ w2t,
                     const float* __restrict__ q, const float* __restrict__ gb0,
                     float* __restrict__ c0) {
    __shared__ float smem[1056];
    int b = blockIdx.x, tid = threadIdx.x;
    if (b < NB_CVT) {
        long i = (long)b * 256 + tid;
        long ntot4 = (NROWS + 1) * 64;
        if (i < ntot4) {
            long i4 = i * 4, nx = NROWS * 256;
            float4 v = make_float4(0.f, 0.f, 0.f, 0.f);
            if (i4 < nx) v = *(const float4*)(x + i4);
            ushort4 o;
            o.x = f2bf_rne(v.x); o.y = f2bf_rne(v.y);
            o.z = f2bf_rne(v.z); o.w = f2bf_rne(v.w);
            *(ushort4*)(xb + i4) = o;
        }
        return;
    }
    b -= NB_CVT;
    const float* W; unsigned short* Wt; int K, N;
    if (b < NB_T0)                  { W = gW0; Wt = w0t; K = 512;  N = 1024; }
    else if (b < NB_T0 + NB_T1)     { b -= NB_T0; W = gW1; Wt = w1t; K = 1024; N = 1024; }
    else if (b < NB_T0 + NB_T1 + NB_T2) { b -= NB_T0 + NB_T1; W = gW2; Wt = w2t; K = 1024; N = 1024; }
    else {
        // c0 = q @ gW0[512:768] + gb0  (8 blocks: 4 j x 2 k)
        b -= NB_T0 + NB_T1 + NB_T2;
        int bx = b & 3, by = b >> 2;
        int j = bx * 256 + tid, k0 = by * 128;
        if (tid < 128) smem[tid] = q[k0 + tid];
        __syncthreads();
        float a = (by == 0) ? gb0[j] : 0.f;
        #pragma unroll 4
        for (int k = 0; k < 128; ++k)
            a += smem[k] * gW0[(size_t)(512 + k0 + k) * 1024 + j];
        atomicAdd(&c0[j], a);
        return;
    }
    int bx = b & 31, by = b >> 5;
    float (*tile)[33] = (float(*)[33])smem;
    int tx = tid & 31, ty = tid >> 5;
    int nb2 = bx * 32, kb = by * 32;
    #pragma unroll
    for (int i = 0; i < 32; i += 8)
        tile[ty + i][tx] = W[(size_t)(kb + ty + i) * N + (nb2 + tx)];
    __syncthreads();
    #pragma unroll
    for (int i = 0; i < 32; i += 8)
        Wt[(size_t)(nb2 + ty + i) * K + (kb + tx)] = f2bf_rne(tile[tx][ty + i]);
}

// ---- small fp32 FC partial (multi-block, atomic K-split) ----
template<bool RELU_IN>
__global__ void fc_partial(const float* __restrict__ in, const float* __restrict__ W,
                           const float* __restrict__ bias, float* __restrict__ out,
                           int N) {
    __shared__ float s_in[128];
    int j = blockIdx.x * 256 + threadIdx.x;
    int k0 = blockIdx.y * 128;
    if (threadIdx.x < 128) {
        float v = in[k0 + threadIdx.x];
        if (RELU_IN) v = fmaxf(v, 0.f);
        s_in[threadIdx.x] = v;
    }
    __syncthreads();
    float acc = (blockIdx.y == 0) ? bias[j] : 0.f;
    #pragma unroll 4
    for (int k = 0; k < 128; ++k)
        acc += s_in[k] * W[(size_t)(k0 + k) * N + j];
    atomicAdd(&out[j], acc);
}

// ================== 256x256 8-phase bf16 MFMA GEMM (in-region reads) =============
// Per phase: barrier; lgkmcnt(0); setprio(1); { ds_reads + STAGE + 16 MFMA, no
// internal fences -> compiler interleaves DS/VALU with MFMA pipe }; setprio(0);
// vmcnt(2); barrier.  vmcnt(2) proves every staged half-tile one full phase
// before its first read (drains pairs ~2 phases / ~2000cy old -> stall-free).
// C(m,n) = A(m x K) * Bt(n x K)^T.  COLSUM=0: Hout=relu(C+bias), LDS-bounce.
// COLSUM=1: masked column-sum of relu(C+bias) atomicAdd into emb.

#define SBAR() __builtin_amdgcn_sched_barrier(0)

#define S_PRE() do { SBAR(); __builtin_amdgcn_s_barrier(); \
    asm volatile("s_waitcnt lgkmcnt(0)" ::: "memory"); SBAR(); \
    __builtin_amdgcn_s_setprio(1); } while (0)

#define S_POST() do { __builtin_amdgcn_s_setprio(0); SBAR(); \
    asm volatile("s_waitcnt vmcnt(2)" ::: "memory"); \
    __builtin_amdgcn_s_barrier(); } while (0)

// stage one half-tile (128 rows x 64 cols bf16 = 16KB) of tile T into buf.
// region 0: B rows 0-127, 1: B rows 128-255, 2: A rows 0-127, 3: A rows 128-255.
#define STAGE(buf, region, T) do { \
    if ((region) >= 2) { \
        const unsigned short* _g = gA + (long)(((region) & 1) * 128) * lda + (long)(T) * 64; \
        char* _d = (char*)&lds[buf][0][((region) & 1) * 128][0] + t * 16; \
        gload_lds16(_g, _d); \
        gload_lds16(_g + 64L * lda, _d + 8192); \
    } else { \
        const unsigned short* _g = gB + (long)(((region) & 1) * 128) * ldb + (long)(T) * 64; \
        char* _d = (char*)&lds[buf][1][((region) & 1) * 128][0] + t * 16; \
        gload_lds16(_g, _d); \
        gload_lds16(_g + 64L * ldb, _d + 8192); \
    } } while (0)

#define LDA4(dst, buf, mbase, ks) do { _Pragma("unroll") for (int _q = 0; _q < 4; ++_q) \
    dst[_q] = *(const short8*)((const char*)&lds[buf][0][arowb + ((mbase) + _q) * 16][0] + ((ks) ? cb1 : cb0)); } while (0)

#define LDB4(dst, buf, ks) do { _Pragma("unroll") for (int _q = 0; _q < 4; ++_q) \
    dst[_q] = *(const short8*)((const char*)&lds[buf][1][browb + _q * 16][0] + ((ks) ? cb1 : cb0)); } while (0)

#define MFMA16(AF, BF, MO) do { _Pragma("unroll") for (int _mf = 0; _mf < 4; ++_mf) { \
    _Pragma("unroll") for (int _nf = 0; _nf < 4; ++_nf) \
        acc[(MO) + _mf][_nf] = __builtin_amdgcn_mfma_f32_16x16x32_bf16(AF[_mf], BF[_nf], acc[(MO) + _mf][_nf], 0, 0, 0); } } while (0)

template<int COLSUM>
__global__ __launch_bounds__(512, 2)
void gemmS(const unsigned short* __restrict__ A, int lda,
           const unsigned short* __restrict__ Bt, int ldb,
           const float* __restrict__ bias, int K,
           unsigned short* __restrict__ Hout,
           float* __restrict__ emb, long row0g, long nvalid,
           int mblocks) {
    __shared__ alignas(16) unsigned short lds[2][2][256][64];  // 128 KiB

    const int t = threadIdx.x;        // 0..511
    // XCD-aware swizzle (bijective since nwg % 8 == 0); n-fastest within chunk
    // so the 4 blocks sharing an A panel are co-resident on one XCD.
    int nwg = gridDim.x, bid = blockIdx.x, swz;
    if ((nwg & 7) == 0) { int cpx = nwg >> 3; swz = (bid & 7) * cpx + (bid >> 3); }
    else swz = bid;
    const int mb = swz >> 2, nb = swz & 3;
    const long m0 = (long)mb * 256;
    const int n0 = nb * 256;

    // staging addresses: thread t covers (row = t>>3 within 64-row group, chunk = t&7)
    const int srow = t >> 3;
    const int ssc = (t & 7) ^ (srow & 7);             // pre-swizzled source chunk
    const unsigned short* gA = A + (m0 + srow) * (long)lda + ssc * 8;
    const unsigned short* gB = Bt + ((long)n0 + srow) * (long)ldb + ssc * 8;

    // ds_read fragment addressing
    const int lane = t & 63;
    const int wv = t >> 6;
    const int wm = wv >> 2, wn = wv & 3;              // 2 M-waves x 4 N-waves
    const int arowb = wm * 128 + (lane & 15);
    const int browb = wn * 64 + (lane & 15);
    const int c0x = (lane >> 4) ^ (lane & 7);
    const int cb0 = c0x * 16;
    const int cb1 = (c0x ^ 4) * 16;

    floatx4 acc[8][4] = {};

    const int NT = K >> 6;            // 64-wide K tiles (8 or 16; even)
    const int NI = NT >> 1;

    short8 bE0[4], bE1[4], bO0[4], bO1[4];
    short8 aE0[4], aE1[4], aE2[4], aE3[4], aO0[4], aO1[4], aO2[4], aO3[4];

    // prologue: tile0 full -> buf0; tile1 B-halves -> buf1; counted wait
    STAGE(0, 0, 0); STAGE(0, 1, 0); STAGE(0, 2, 0); STAGE(0, 3, 0);
    STAGE(1, 0, 1); STAGE(1, 1, 1);
    asm volatile("s_waitcnt vmcnt(4)" ::: "memory");   // tile0 landed; T1.B in flight
    SBAR();
    __builtin_amdgcn_s_barrier();
    SBAR();
    LDB4(bE0, 0, 0); LDA4(aE0, 0, 0, 0);               // drained by ph1's lgkm(0)

    for (int i = 0; i < NI; ++i) {
        const int O = 2 * i + 1;
        int N2 = 2 * i + 2; if (N2 >= NT) N2 = 0;      // wrap: redundant loads, safe
        int P2 = 2 * i + 3; if (P2 >= NT) P2 = 1;

        // ---- ph1 ----
        S_PRE();
        LDA4(aE1, 0, 4, 0);
        STAGE(1, 2, O);
        MFMA16(aE0, bE0, 0);
        S_POST();
        // ---- ph2 ----
        S_PRE();
        LDB4(bE1, 0, 1); LDA4(aE2, 0, 0, 1);
        STAGE(1, 3, O);
        MFMA16(aE1, bE0, 4);
        S_POST();
        // ---- ph3 ----
        S_PRE();
        LDA4(aE3, 0, 4, 1);
        STAGE(0, 0, N2);
        MFMA16(aE2, bE1, 0);
        S_POST();
        // ---- ph4 ----
        S_PRE();
        LDB4(bO0, 1, 0); LDA4(aO0, 1, 0, 0);
        STAGE(0, 1, N2);
        MFMA16(aE3, bE1, 4);
        S_POST();
        // ---- ph5 ----
        S_PRE();
        LDA4(aO1, 1, 4, 0);
        STAGE(0, 2, N2);
        MFMA16(aO0, bO0, 0);
        S_POST();
        // ---- ph6 ----
        S_PRE();
        LDB4(bO1, 1, 1); LDA4(aO2, 1, 0, 1);
        STAGE(0, 3, N2);
        MFMA16(aO1, bO0, 4);
        S_POST();
        // ---- ph7 ----
        S_PRE();
        LDA4(aO3, 1, 4, 1);
        STAGE(1, 0, P2);
        MFMA16(aO2, bO1, 0);
        S_POST();
        // ---- ph8 ----
        S_PRE();
        LDB4(bE0, 0, 0); LDA4(aE0, 0, 0, 0);
        STAGE(1, 1, P2);
        MFMA16(aO3, bO1, 4);
        S_POST();
    }
    asm volatile("s_waitcnt vmcnt(0) lgkmcnt(0)" ::: "memory");
    SBAR();
    __builtin_amdgcn_s_barrier();   // LDS now free for epilogue reuse

    // epilogue: C/D layout col = lane&15, row = (lane>>4)*4 + j
    if (COLSUM == 0) {
        // 1) acc -> LDS as one 256x256 bf16 tile ([row][512B], col-bytes XOR row-swizzled)
        char* slb = (char*)&lds[0][0][0][0];
        #pragma unroll
        for (int nf = 0; nf < 4; ++nf) {
            int ncol = wn * 64 + nf * 16 + (lane & 15);        // 0..255 in tile
            float bv = bias[n0 + ncol];
            #pragma unroll
            for (int mf = 0; mf < 8; ++mf) {
                int rbase = wm * 128 + mf * 16 + ((lane >> 4) << 2);
                #pragma unroll
                for (int j = 0; j < 4; ++j) {
                    int row = rbase + j;
                    float v = fmaxf(acc[mf][nf][j] + bv, 0.f);
                    int byte = row * 512 + ((ncol * 2) ^ ((row & 7) << 4));
                    *(unsigned short*)(slb + byte) = f2bf_rne(v);
                }
            }
        }
        __syncthreads();
        // 2) LDS -> global, wave-contiguous: per instruction, lanes (t&31) cover one
        //    full 512B row-segment (8 full 64B lines); t>>5 selects the row.
        {
            int rsub = t >> 5;              // 0..15
            int cb = (t & 31) * 16;         // 0..496
            #pragma unroll
            for (int i2 = 0; i2 < 16; ++i2) {
                int row = i2 * 16 + rsub;
                const char* src = slb + row * 512 + (cb ^ ((row & 7) << 4));
                uint32x4 v = *(const uint32x4*)src;
                char* dst = (char*)Hout + ((size_t)(m0 + row) * HGDIM + n0) * 2 + cb;
                *(uint32x4*)dst = v;
            }
        }
    } else {
        #pragma unroll
        for (int nf = 0; nf < 4; ++nf) {
            int ncol = n0 + wn * 64 + nf * 16 + (lane & 15);
            float bv = bias[ncol];
            float cs = 0.f;
            #pragma unroll
            for (int mf = 0; mf < 8; ++mf) {
                long rbase = row0g + m0 + wm * 128 + mf * 16 + ((lane >> 4) << 2);
                #pragma unroll
                for (int j = 0; j < 4; ++j) {
                    float v = fmaxf(acc[mf][nf][j] + bv, 0.f);
                    if (rbase + j < nvalid) cs += v;
                }
            }
            cs += __shfl_xor(cs, 16);
            cs += __shfl_xor(cs, 32);
            if ((lane >> 4) == 0) atomicAdd(&emb[ncol], cs);
        }
    }
}

extern "C" void kernel_launch(void* const* d_in, const int* in_sizes, int n_in,
                              void* d_out, int out_size, void* d_ws, size_t ws_size,
                              hipStream_t stream) {
    const float* x   = (const float*)d_in[0];
    const float* q   = (const float*)d_in[1];
    const float* gW0 = (const float*)d_in[2];
    const float* gb0 = (const float*)d_in[3];
    const float* gW1 = (const float*)d_in[4];
    const float* gb1 = (const float*)d_in[5];
    const float* gW2 = (const float*)d_in[6];
    const float* gb2 = (const float*)d_in[7];
    const float* fW0 = (const float*)d_in[8];
    const float* fb0 = (const float*)d_in[9];
    const float* fW1 = (const float*)d_in[10];
    const float* fb1 = (const float*)d_in[11];
    const float* fW2 = (const float*)d_in[12];
    const float* fb2 = (const float*)d_in[13];
    float* out = (float*)d_out;

    char* ws = (char*)d_ws;
    size_t off = 0;
    auto alloc = [&](size_t bytes) -> char* {
        char* p = ws + off;
        off += (bytes + 255) & ~(size_t)255;
        return p;
    };
    unsigned short* xb  = (unsigned short*)alloc((NROWS + 1) * 256 * 2);  // +1 zero row
    unsigned short* w0t = (unsigned short*)alloc((size_t)1024 * 512 * 2);
    unsigned short* w1t = (unsigned short*)alloc((size_t)1024 * 1024 * 2);
    unsigned short* w2t = (unsigned short*)alloc((size_t)1024 * 1024 * 2);
    float* c0  = (float*)alloc(4096);
    float* emb = (float*)alloc(4096);
    float* e1  = (float*)alloc(4096);
    float* e2  = (float*)alloc(4096);
    size_t fixed = off;
    size_t avail = (ws_size > fixed) ? ws_size - fixed : 0;
    long CR = (long)((avail / 2) / (HGDIM * 2));
    CR = (CR / 512) * 512;              // keep mblocks even -> nwg % 8 == 0
    if (CR > NROWS) CR = NROWS;
    if (CR < 512) CR = 512;
    unsigned short* H0 = (unsigned short*)alloc((size_t)CR * HGDIM * 2);
    unsigned short* H1 = (unsigned short*)alloc((size_t)CR * HGDIM * 2);

    hipMemsetAsync(c0, 0, 4 * 4096, stream);   // c0 + emb + e1 + e2
    hipMemsetAsync(out, 0, 256 * sizeof(float), stream);

    prep<<<dim3(NB_CVT + NB_T0 + NB_T1 + NB_T2 + 8), 256, 0, stream>>>(
        x, xb, gW0, w0t, gW1, w1t, gW2, w2t, q, gb0, c0);

    for (long r0 = 0; r0 < NROWS; r0 += CR) {
        long rows = NROWS - r0; if (rows > CR) rows = CR;
        int mblocks = (int)(rows / 256);
        dim3 g((unsigned)(mblocks * 4));
        // H0 = relu(x[:-1]*W0a + x[1:]*W0b + c0): A rows are overlapping 512-windows of xb
        gemmS<0><<<g, 512, 0, stream>>>(xb + r0 * 256, 256, w0t, 512, c0, 512,
                                        H0, nullptr, 0, 0, mblocks);
        gemmS<0><<<g, 512, 0, stream>>>(H0, 1024, w1t, 1024, gb1, 1024,
                                        H1, nullptr, 0, 0, mblocks);
        gemmS<1><<<g, 512, 0, stream>>>(H1, 1024, w2t, 1024, gb2, 1024,
                                        nullptr, emb, r0, NVALID, mblocks);
    }

    fc_partial<false><<<dim3(4, 8), 256, 0, stream>>>(emb, fW0, fb0, e1, 1024);
    fc_partial<true><<<dim3(2, 8), 256, 0, stream>>>(e1, fW1, fb1, e2, 512);
    fc_partial<true><<<dim3(1, 4), 256, 0, stream>>>(e2, fW2, fb2, out, 256);
}